// Round 2
// baseline (352.830 us; speedup 1.0000x reference)
//
#include <hip/hip_runtime.h>
#include <cstdint>
#include <cstddef>

#define CIN   128
#define COUT  256
#define HW    64
#define NSP   4096      // 64*64 spatial
#define KTOT  1152      // CIN*9
#define BATCH 32
#define PDROP 0.2f
#define LDT   40        // fallback conv LDS stride (bf16 elems)

__device__ __forceinline__ unsigned short f2bf(float f) {
    unsigned int u = __builtin_bit_cast(unsigned int, f);
    u += 0x7fffu + ((u >> 16) & 1u);   // round-to-nearest-even
    return (unsigned short)(u >> 16);
}

// 128 B of guaranteed zeros for OOB halo DMA source (never written)
__device__ __align__(16) unsigned short g_zeros[64] = {0};

// async global->LDS, 16 B per lane; LDS dest = wave-uniform base + lane*16
__device__ __forceinline__ void gl_lds16(const unsigned short* g, unsigned short* l) {
    __builtin_amdgcn_global_load_lds(
        (const __attribute__((address_space(1))) unsigned int*)g,
        (__attribute__((address_space(3))) unsigned int*)l,
        16, 0, 0);
}

// ---------------------------------------------------------------------------
// Fused pre-pass (single launch):
//  blocks [0,4096):   per-sample masked bf16 weights, tap-major wt[bo][r*128+i]
//                     (2 bo per block). Thread-per-channel: LDS writes are
//                     2-way bank-aliased (free), no div-by-9.
//  blocks [4096,6144): x NCHW fp32 -> xt[b][hw][ch] bf16 (NHWC).
//                     Channel-pair u32 tile, stride 65 u32: 2-way free both phases.
__global__ __launch_bounds__(256) void prepass(
        const float* __restrict__ weight, const float* __restrict__ u_w,
        const float* __restrict__ x,
        unsigned short* __restrict__ wt, unsigned short* __restrict__ xt)
{
    __shared__ unsigned int shp[64 * 65];          // 16640 B (>= 2*1152 u16)
    unsigned short* sh16 = reinterpret_cast<unsigned short*>(shp);
    const int t256 = threadIdx.x;

    if (blockIdx.x < 4096) {
        const int half = t256 >> 7;                // 0/1: which bo
        const int i    = t256 & 127;               // channel
        const int bo   = blockIdx.x * 2 + half;    // b*COUT + o
        const int o    = bo & (COUT - 1);
        unsigned short* tile = sh16 + half * KTOT;
        const float* wsrc = weight + (size_t)o  * KTOT + i * 9;
        const float* usrc = u_w    + (size_t)bo * KTOT + i * 9;
        float wv9[9], uv9[9];
        #pragma unroll
        for (int r = 0; r < 9; ++r) { wv9[r] = wsrc[r]; uv9[r] = usrc[r]; }
        #pragma unroll
        for (int r = 0; r < 9; ++r)               // bank = (i/2)%32: 2-way free
            tile[r * CIN + i] = f2bf((uv9[r] > PDROP) ? wv9[r] : 0.f);
        __syncthreads();
        const uint4* src = reinterpret_cast<const uint4*>(tile);
        uint4* dst = reinterpret_cast<uint4*>(wt + (size_t)bo * KTOT);
        dst[i] = src[i];                           // 144 uint4 per tile
        if (i < 16) dst[128 + i] = src[128 + i];
    } else {
        const int bidx = blockIdx.x - 4096;
        const int b    = bidx >> 6;
        const int hw0  = (bidx & 63) * 64;
        const int ib   = t256 >> 4;                // 0..15
        const int hw4  = (t256 & 15) * 4;          // local hw row group
        #pragma unroll
        for (int j = 0; j < 4; ++j) {
            const int p = ib + 16 * j;             // channel-pair 0..63
            const float4 v0 = *reinterpret_cast<const float4*>(
                x + ((size_t)(b * CIN + 2 * p)) * NSP + hw0 + hw4);
            const float4 v1 = *reinterpret_cast<const float4*>(
                x + ((size_t)(b * CIN + 2 * p + 1)) * NSP + hw0 + hw4);
            const float e0[4] = {v0.x, v0.y, v0.z, v0.w};
            const float e1[4] = {v1.x, v1.y, v1.z, v1.w};
            #pragma unroll
            for (int c = 0; c < 4; ++c) {
                const unsigned int val =
                    (unsigned int)f2bf(e0[c]) | ((unsigned int)f2bf(e1[c]) << 16);
                shp[(hw4 + c) * 65 + p] = val;     // bank=(hw+p)%32: 2-way free
            }
        }
        __syncthreads();
        #pragma unroll
        for (int j = 0; j < 4; ++j) {
            const int idx  = j * 256 + t256;       // 0..1023
            const int row  = idx >> 4;             // hw_loc 0..63
            const int part = idx & 15;             // 16 B chunk (4 u32 pairs)
            uint4 v;
            v.x = shp[row * 65 + part * 4 + 0];
            v.y = shp[row * 65 + part * 4 + 1];
            v.z = shp[row * 65 + part * 4 + 2];
            v.w = shp[row * 65 + part * 4 + 3];
            *reinterpret_cast<uint4*>(
                xt + ((size_t)(b * NSP + hw0 + row)) * CIN + part * 8) = v;
        }
    }
}

// ---------------------------------------------------------------------------
// Main conv v6: implicit GEMM, LDS-resident X-tile, A-fragments loaded
// DIRECTLY to registers from global (tap-major wt makes each fragment a
// contiguous 16 B at base+imm offset; L1 catches the 2x intra-block reuse).
// This removes the A-tile LDS round-trip and ALL per-tap barriers: only
// 3 __syncthreads per block (X slab staging). Waves free-run through the
// 18 k-phases per slab with a depth-1 register ping-pong on A; latency is
// covered by the phase body + 3 blocks/CU TLP (12 waves).
// XCD-clustered block swizzle keeps each sample's wt panel + xt slab L2-hot.
__global__ __launch_bounds__(256, 3) void conv_v6(
        const unsigned short* __restrict__ wt,
        const unsigned short* __restrict__ xt,
        const float* __restrict__ bias, const float* __restrict__ u_b,
        float* __restrict__ out)
{
    using frag  = __attribute__((ext_vector_type(8))) short;
    using f32x4 = __attribute__((ext_vector_type(4))) float;

    __shared__ unsigned short Xs[4 * 66 * 64];     // 33792 B resident x-tile

    const int tid  = threadIdx.x;
    const int lane = tid & 63;
    const int q    = lane >> 4;
    const int l15  = lane & 15;
    const int wv   = tid >> 6;
    const int wm   = (wv >> 1) * 64;
    const int wn   = (wv & 1) * 64;
    const int wnrow = wn >> 6;                     // 0 or 1: tile spatial row

    // ---- XCD-clustered bijective swizzle (grid = 32 x 2 x 32 = 2048, %8==0)
    const int f   = blockIdx.x + 32 * blockIdx.y + 64 * blockIdx.z;
    const int wid = (f & 7) * 256 + (f >> 3);
    const int b   = wid >> 6;
    const int m0  = ((wid >> 5) & 1) * 128;
    const int n0  = (wid & 31) * 128;
    const int ph0 = n0 >> 6;                       // first global image row

    const unsigned short* wtb = wt + (size_t)(b * COUT + m0) * KTOT;
    const unsigned short* xtb = xt + (size_t)b * NSP * CIN;

    // ---- A-fragment register-load bases: lane (q,l15), row = wm+mi*16+l15.
    // Fragment for (tap,slab,ki): 16 B at base + (tap*128 + slab*64 + ki*32)*2
    const char* gAr[4];
    #pragma unroll
    for (int mi = 0; mi < 4; ++mi)
        gAr[mi] = reinterpret_cast<const char*>(
            wtb + (size_t)(wm + mi * 16 + l15) * KTOT + q * 8);

    // ---- X-DMA map: wave wv stages X row rr=wv (global row ph0-1+wv).
    const int kcl = (lane & 7) ^ ((1 + (lane >> 3)) & 7);
    const int xsrc_lane = (lane >> 3) * CIN + kcl * 8;   // u16 offset in xt row
    const int hhx = ph0 - 1 + wv;
    const bool vrow = ((unsigned)hhx < 64u);
    unsigned short* const xdst = &Xs[(wv * 66 + 1) * 64];

    // ---- B frag-read constants (XOR chunk swizzle, as v4)
    int xoff[4];
    #pragma unroll
    for (int ni = 0; ni < 4; ++ni) xoff[ni] = (ni * 16 + l15 + 1) * 64;
    int xr[3][2];
    #pragma unroll
    for (int dxi = 0; dxi < 3; ++dxi)
        #pragma unroll
        for (int ki = 0; ki < 2; ++ki)
            xr[dxi][ki] = ((ki * 4 + q) ^ ((l15 + dxi) & 7)) * 8;

    f32x4 acc[4][4];
    #pragma unroll
    for (int i = 0; i < 4; ++i)
        #pragma unroll
        for (int j = 0; j < 4; ++j)
            acc[i][j] = (f32x4){0.f, 0.f, 0.f, 0.f};

    // ---- zero the column-halo cells of Xs once (cc=0 and cc=65, all 4 rows)
    {
        const int cell = tid >> 5;                 // 0..7
        const int rr   = cell >> 1;
        const int cc   = (cell & 1) ? 65 : 0;
        *reinterpret_cast<unsigned int*>(
            &Xs[(rr * 66 + cc) * 64 + (tid & 31) * 2]) = 0u;
    }

    auto stage_x = [&](int i0) {
        const unsigned short* sx = vrow
            ? xtb + (size_t)hhx * HW * CIN + i0 + xsrc_lane
            : g_zeros;
        #pragma unroll
        for (int g = 0; g < 8; ++g)
            gl_lds16(vrow ? (sx + g * 8 * CIN) : sx, xdst + g * 512);
    };

    #pragma unroll
    for (int s2 = 0; s2 < 2; ++s2) {
        const int i0 = s2 * 64;

        if (s2) __syncthreads();                   // slab0 reads complete
        stage_x(i0);
        __syncthreads();                           // drains vmcnt+lgkm: X (and halo) ready

        // ---- 18 k-phases (9 taps x 2 ki), A depth-1 register ping-pong
        frag afr[2][4];                            // all indices compile-time (full unroll)
        #pragma unroll
        for (int mi = 0; mi < 4; ++mi)
            afr[0][mi] = *reinterpret_cast<const frag*>(gAr[mi] + (i0 * 2));

        #pragma unroll
        for (int p = 0; p < 18; ++p) {
            const int cur = p & 1;
            if (p + 1 < 18) {
                const int koff = (((p + 1) >> 1) * 128 + i0 + ((p + 1) & 1) * 32) * 2;
                #pragma unroll
                for (int mi = 0; mi < 4; ++mi)
                    afr[cur ^ 1][mi] = *reinterpret_cast<const frag*>(gAr[mi] + koff);
            }
            const int tap = p >> 1;
            const int ki  = p & 1;
            const int dy  = tap / 3 - 1;
            const int dx  = tap - 3 * (tap / 3) - 1;
            const int dxi = dx + 1;
            const int cb  = (wnrow + dy + 1) * 4224 + dx * 64;  // 66*64 = 4224

            frag bfr[4];
            #pragma unroll
            for (int ni = 0; ni < 4; ++ni)
                bfr[ni] = *reinterpret_cast<const frag*>(
                    &Xs[cb + xoff[ni] + xr[dxi][ki]]);

            __builtin_amdgcn_s_setprio(1);
            #pragma unroll
            for (int mi = 0; mi < 4; ++mi)
                #pragma unroll
                for (int ni = 0; ni < 4; ++ni)
                    acc[mi][ni] = __builtin_amdgcn_mfma_f32_16x16x32_bf16(
                        afr[cur][mi], bfr[ni], acc[mi][ni], 0, 0, 0);
            __builtin_amdgcn_s_setprio(0);
        }
    }

    // ---- epilogue: D row=(q*4+reg), col=l15 ; add dropped-out bias
    float* ob = out + (size_t)b * COUT * NSP;
    #pragma unroll
    for (int mi = 0; mi < 4; ++mi) {
        #pragma unroll
        for (int rg = 0; rg < 4; ++rg) {
            const int o  = m0 + wm + mi * 16 + q * 4 + rg;
            const float bvv = (u_b[b * COUT + o] > PDROP) ? bias[o] : 0.f;
            float* orow = ob + (size_t)o * NSP + n0 + wn + l15;
            #pragma unroll
            for (int ni = 0; ni < 4; ++ni)
                orow[ni * 16] = acc[mi][ni][rg] + bvv;
        }
    }
}

// ---------------------------------------------------------------------------
// Fallback (round-1 kernel): used only if workspace is too small.
template<bool USE_WS>
__global__ __launch_bounds__(256) void conv_fb(
        const float* __restrict__ x, const float* __restrict__ weight,
        const float* __restrict__ bias, const float* __restrict__ u_w,
        const float* __restrict__ u_b, const unsigned short* __restrict__ wt,
        float* __restrict__ out)
{
    using frag  = __attribute__((ext_vector_type(8))) short;
    using f32x4 = __attribute__((ext_vector_type(4))) float;

    __shared__ unsigned short As[128 * LDT];
    __shared__ unsigned short Bs[128 * LDT];

    const int tid  = threadIdx.x;
    const int lane = tid & 63;
    const int q    = lane >> 4;
    const int l15  = lane & 15;
    const int wv   = tid >> 6;
    const int wm   = (wv >> 1) * 64;
    const int wn   = (wv & 1) * 64;

    const int b  = blockIdx.z;
    const int m0 = blockIdx.y * 128;
    const int n0 = blockIdx.x * 128;

    const int arow = tid >> 1;
    const int acol = (tid & 1) * 16;
    const int pn = tid & 127;
    const int kh = (tid >> 7) * 16;
    const int p  = n0 + pn;
    const int ph = p >> 6;
    const int pw = p & 63;

    const float* xb = x + (size_t)b * CIN * NSP;

    f32x4 acc[4][4];
    #pragma unroll
    for (int i = 0; i < 4; ++i)
        #pragma unroll
        for (int j = 0; j < 4; ++j)
            acc[i][j] = (f32x4){0.f, 0.f, 0.f, 0.f};

    const int a_rd = (wm + l15) * LDT + q * 8;
    const int b_rd = (wn + l15) * LDT + q * 8;

    for (int s = 0; s < 36; ++s) {
        const int r  = s >> 2;
        const int i0 = (s & 3) * 32;
        const int k0 = s * 32;

        uint4 av0, av1;
        float aw[16], au[16];
        if (USE_WS) {
            const uint4* src = reinterpret_cast<const uint4*>(
                wt + ((size_t)(b * COUT + m0 + arow)) * KTOT + k0 + acol);
            av0 = src[0];
            av1 = src[1];
        } else {
            const float* wsrc = weight + (size_t)(m0 + arow) * KTOT;
            const float* usrc = u_w + (size_t)(b * COUT + m0 + arow) * KTOT;
            #pragma unroll
            for (int ii = 0; ii < 16; ++ii) {
                const int kk = (i0 + acol + ii) * 9 + r;
                aw[ii] = wsrc[kk];
                au[ii] = usrc[kk];
            }
        }

        const int hh = ph + (r / 3) - 1;
        const int ww = pw + (r % 3) - 1;
        float bx[16];
        #pragma unroll
        for (int j = 0; j < 16; ++j) bx[j] = 0.f;
        if (((unsigned)hh < 64u) && ((unsigned)ww < 64u)) {
            const float* xsrc = xb + (size_t)(i0 + kh) * NSP + hh * HW + ww;
            #pragma unroll
            for (int j = 0; j < 16; ++j) bx[j] = xsrc[(size_t)j * NSP];
        }

        __syncthreads();

        if (USE_WS) {
            uint4* d = reinterpret_cast<uint4*>(&As[arow * LDT + acol]);
            d[0] = av0; d[1] = av1;
        } else {
            union { unsigned short u16[16]; uint4 v[2]; } tu;
            #pragma unroll
            for (int ii = 0; ii < 16; ++ii)
                tu.u16[ii] = f2bf((au[ii] > PDROP) ? aw[ii] : 0.f);
            uint4* d = reinterpret_cast<uint4*>(&As[arow * LDT + acol]);
            d[0] = tu.v[0]; d[1] = tu.v[1];
        }
        {
            union { unsigned short u16[16]; uint4 v[2]; } tu;
            #pragma unroll
            for (int j = 0; j < 16; ++j) tu.u16[j] = f2bf(bx[j]);
            uint4* d = reinterpret_cast<uint4*>(&Bs[pn * LDT + kh]);
            d[0] = tu.v[0]; d[1] = tu.v[1];
        }

        __syncthreads();

        frag af[4], bfr[4];
        #pragma unroll
        for (int mi = 0; mi < 4; ++mi)
            af[mi] = *reinterpret_cast<const frag*>(&As[a_rd + mi * 16 * LDT]);
        #pragma unroll
        for (int ni = 0; ni < 4; ++ni)
            bfr[ni] = *reinterpret_cast<const frag*>(&Bs[b_rd + ni * 16 * LDT]);
        #pragma unroll
        for (int mi = 0; mi < 4; ++mi)
            #pragma unroll
            for (int ni = 0; ni < 4; ++ni)
                acc[mi][ni] = __builtin_amdgcn_mfma_f32_16x16x32_bf16(
                    af[mi], bfr[ni], acc[mi][ni], 0, 0, 0);
    }

    float* ob = out + (size_t)b * COUT * NSP;
    #pragma unroll
    for (int mi = 0; mi < 4; ++mi) {
        #pragma unroll
        for (int rg = 0; rg < 4; ++rg) {
            const int o = m0 + wm + mi * 16 + q * 4 + rg;
            const float bvv = (u_b[b * COUT + o] > PDROP) ? bias[o] : 0.f;
            float* orow = ob + (size_t)o * NSP + n0 + wn + l15;
            #pragma unroll
            for (int ni = 0; ni < 4; ++ni)
                orow[ni * 16] = acc[mi][ni][rg] + bvv;
        }
    }
}

extern "C" void kernel_launch(void* const* d_in, const int* in_sizes, int n_in,
                              void* d_out, int out_size, void* d_ws, size_t ws_size,
                              hipStream_t stream)
{
    const float* x      = (const float*)d_in[0];
    const float* weight = (const float*)d_in[1];
    const float* bias   = (const float*)d_in[2];
    const float* u_w    = (const float*)d_in[3];
    const float* u_b    = (const float*)d_in[4];
    float* out = (float*)d_out;

    const size_t wt_bytes = (size_t)BATCH * COUT * KTOT * sizeof(unsigned short); // 18.87 MB
    const size_t xt_bytes = (size_t)BATCH * NSP * CIN * sizeof(unsigned short);   // 33.55 MB
    dim3 grid(NSP / 128, COUT / 128, BATCH);   // 32 x 2 x 32 = 2048 blocks

    if (ws_size >= wt_bytes + xt_bytes) {
        unsigned short* wtp = (unsigned short*)d_ws;
        unsigned short* xtp = (unsigned short*)((char*)d_ws + wt_bytes);
        prepass<<<4096 + 2048, 256, 0, stream>>>(weight, u_w, x, wtp, xtp);
        conv_v6<<<grid, 256, 0, stream>>>(wtp, xtp, bias, u_b, out);
    } else if (ws_size >= wt_bytes) {
        unsigned short* wtp = (unsigned short*)d_ws;
        // reuse prepass weight half only
        prepass<<<4096, 256, 0, stream>>>(weight, u_w, x, wtp, nullptr);
        conv_fb<true><<<grid, 256, 0, stream>>>(x, weight, bias, u_w, u_b, wtp, out);
    } else {
        conv_fb<false><<<grid, 256, 0, stream>>>(x, weight, bias, u_w, u_b, nullptr, out);
    }
}

// Round 3
// 288.319 us; speedup vs baseline: 1.2237x; 1.2237x over previous
//
#include <hip/hip_runtime.h>
#include <cstdint>
#include <cstddef>

#define CIN   128
#define COUT  256
#define HW    64
#define NSP   4096      // 64*64 spatial
#define KTOT  1152      // CIN*9
#define BATCH 32
#define PDROP 0.2f
#define LDT   40        // fallback conv LDS stride (bf16 elems)
#define WLD   1160      // prepass weight tile stride (elems)

__device__ __forceinline__ unsigned short f2bf(float f) {
    unsigned int u = __builtin_bit_cast(unsigned int, f);
    u += 0x7fffu + ((u >> 16) & 1u);   // round-to-nearest-even
    return (unsigned short)(u >> 16);
}

// 128 B of guaranteed zeros for OOB halo DMA source (never written)
__device__ __align__(16) unsigned short g_zeros[64] = {0};

// async global->LDS, 16 B per lane; LDS dest = wave-uniform base + lane*16
__device__ __forceinline__ void gl_lds16(const unsigned short* g, unsigned short* l) {
    __builtin_amdgcn_global_load_lds(
        (const __attribute__((address_space(1))) unsigned int*)g,
        (__attribute__((address_space(3))) unsigned int*)l,
        16, 0, 0);
}

// ---------------------------------------------------------------------------
// wt2 layout (16-B chunk units):
//   chunk = (((((b*2+mb)*2+slab)*9+tap)*2+ki)*2+wm2)*256 + mi*64 + (q*16+l15)
// Conv A-load for wave(wm2), phase(slab,tap,ki), frag mi is then exactly
//   base + lane*16  (lane = q*16+l15)  -> ideal coalesced 1 KiB/instruction.
// Chunk content: masked bf16 weight row o = mb*128+wm2*64+mi*16+l15,
//   channels i = slab*64+ki*32+q*8 .. +8, tap r  (flat OIHW k = i*9+r).
// ---------------------------------------------------------------------------
// Fused pre-pass (single launch):
//  blocks [0,512):    weight -> wt2 fragment-major. Block owns (b,mb,wm2,mi)
//                     = 16 rows; builds tap-major tile in LDS, then writes
//                     contiguous 1-KB coalesced runs.
//  blocks [512,2560): x NCHW fp32 -> xt[b][hw][ch] bf16 (NHWC), via u32
//                     channel-pair tile stride 65 (2-way free both phases).
__global__ __launch_bounds__(256) void prepass(
        const float* __restrict__ weight, const float* __restrict__ u_w,
        const float* __restrict__ x,
        unsigned short* __restrict__ wt2, unsigned short* __restrict__ xt)
{
    __shared__ __align__(16) unsigned char smem[16 * WLD * 2];   // 37120 B
    const int t256 = threadIdx.x;

    if (blockIdx.x < 512) {
        unsigned short* tile16 = reinterpret_cast<unsigned short*>(smem);
        const int wb  = blockIdx.x;
        const int b   = wb >> 4;
        const int mb  = (wb >> 3) & 1;
        const int wm2 = (wb >> 2) & 1;
        const int mi  = wb & 3;
        const int obase = mb * 128 + wm2 * 64 + mi * 16;

        // ---- load + mask + transpose to tap-major tile16[row][r*128+i]
        const int row = t256 >> 4;                 // 0..15
        const int sub = t256 & 15;                 // 16 threads per row
        const int o   = obase + row;
        const float* wsrc = weight + (size_t)o * KTOT;
        const float* usrc = u_w + (size_t)(b * COUT + o) * KTOT;
        unsigned short* trow = tile16 + row * WLD;
        #pragma unroll
        for (int j = 0; j < 18; ++j) {
            const int kf = sub * 72 + j * 4;       // 0..1148
            const float4 wv = *reinterpret_cast<const float4*>(wsrc + kf);
            const float4 uv = *reinterpret_cast<const float4*>(usrc + kf);
            const float w4[4] = {wv.x, wv.y, wv.z, wv.w};
            const float u4[4] = {uv.x, uv.y, uv.z, uv.w};
            #pragma unroll
            for (int e = 0; e < 4; ++e) {
                const int ks = kf + e;             // flat OIHW: ks = i*9 + r
                const int i  = ks / 9;
                const int r  = ks - 9 * i;
                trow[r * CIN + i] = f2bf((u4[e] > PDROP) ? w4[e] : 0.f);
            }
        }
        __syncthreads();

        // ---- write phase: 36 runs x 1 KB, fully coalesced
        const size_t blk16 = ((size_t)(b * 2 + mb)) * 18432;   // chunk units
        #pragma unroll
        for (int s = 0; s < 9; ++s) {
            const int g     = s * 256 + t256;      // 0..2303
            const int run   = g >> 6;              // 0..35
            const int inner = g & 63;              // q*16 + l15
            const int slab  = run >= 18;
            const int rr    = run - slab * 18;
            const int tap   = rr >> 1;
            const int ki    = rr & 1;
            const int q     = inner >> 4;
            const int il15  = inner & 15;
            const uint4 v = *reinterpret_cast<const uint4*>(
                &tile16[il15 * WLD + tap * CIN + slab * 64 + ki * 32 + q * 8]);
            const size_t dst16 = blk16
                + (size_t)(((slab * 9 + tap) * 2 + ki) * 2 + wm2) * 256
                + mi * 64 + inner;
            *reinterpret_cast<uint4*>(wt2 + dst16 * 8) = v;
        }
    } else {
        unsigned int* shp = reinterpret_cast<unsigned int*>(smem);
        const int bidx = blockIdx.x - 512;
        const int b    = bidx >> 6;
        const int hw0  = (bidx & 63) * 64;
        const int ib   = t256 >> 4;                // 0..15
        const int hw4  = (t256 & 15) * 4;          // local hw row group
        #pragma unroll
        for (int j = 0; j < 4; ++j) {
            const int p = ib + 16 * j;             // channel-pair 0..63
            const float4 v0 = *reinterpret_cast<const float4*>(
                x + ((size_t)(b * CIN + 2 * p)) * NSP + hw0 + hw4);
            const float4 v1 = *reinterpret_cast<const float4*>(
                x + ((size_t)(b * CIN + 2 * p + 1)) * NSP + hw0 + hw4);
            const float e0[4] = {v0.x, v0.y, v0.z, v0.w};
            const float e1[4] = {v1.x, v1.y, v1.z, v1.w};
            #pragma unroll
            for (int c = 0; c < 4; ++c) {
                const unsigned int val =
                    (unsigned int)f2bf(e0[c]) | ((unsigned int)f2bf(e1[c]) << 16);
                shp[(hw4 + c) * 65 + p] = val;     // bank=(hw+p)%32: 2-way free
            }
        }
        __syncthreads();
        #pragma unroll
        for (int j = 0; j < 4; ++j) {
            const int idx  = j * 256 + t256;       // 0..1023
            const int row  = idx >> 4;             // hw_loc 0..63
            const int part = idx & 15;             // 16 B chunk (4 u32 pairs)
            uint4 v;
            v.x = shp[row * 65 + part * 4 + 0];
            v.y = shp[row * 65 + part * 4 + 1];
            v.z = shp[row * 65 + part * 4 + 2];
            v.w = shp[row * 65 + part * 4 + 3];
            *reinterpret_cast<uint4*>(
                xt + ((size_t)(b * NSP + hw0 + row)) * CIN + part * 8) = v;
        }
    }
}

// ---------------------------------------------------------------------------
// Main conv v7: implicit GEMM, LDS-resident X-tile (v4's proven swizzled DMA),
// A-fragments loaded direct-to-register from fragment-major wt2 with ideal
// coalescing (base + lane*16, 1 KiB/instr) and a DEPTH-2 register ring
// (ring-of-3, static indices). Only 3 barriers per block; waves free-run
// through 36 k-phases; compiler emits counted vmcnt(8) for the ring (T4).
// XCD-clustered swizzle keeps wt2 panel (288 KB) + xt slab L2-resident.
__global__ __launch_bounds__(256, 3) void conv_v7(
        const unsigned short* __restrict__ wt2,
        const unsigned short* __restrict__ xt,
        const float* __restrict__ bias, const float* __restrict__ u_b,
        float* __restrict__ out)
{
    using frag  = __attribute__((ext_vector_type(8))) short;
    using f32x4 = __attribute__((ext_vector_type(4))) float;

    __shared__ unsigned short Xs[4 * 66 * 64];     // 33792 B resident x-tile

    const int tid  = threadIdx.x;
    const int lane = tid & 63;
    const int q    = lane >> 4;
    const int l15  = lane & 15;
    const int wv   = tid >> 6;
    const int wm   = (wv >> 1) * 64;
    const int wn   = (wv & 1) * 64;
    const int wnrow = wn >> 6;                     // 0 or 1: tile spatial row
    const int wm2  = wv >> 1;

    // ---- XCD-clustered bijective swizzle (grid = 32 x 2 x 32 = 2048, %8==0)
    const int f   = blockIdx.x + 32 * blockIdx.y + 64 * blockIdx.z;
    const int wid = (f & 7) * 256 + (f >> 3);
    const int b   = wid >> 6;
    const int m0  = ((wid >> 5) & 1) * 128;
    const int n0  = (wid & 31) * 128;
    const int mb  = m0 >> 7;
    const int ph0 = n0 >> 6;                       // first global image row

    const unsigned short* xtb = xt + (size_t)b * NSP * CIN;

    // ---- A-fragment base pointers (elems): wt2 chunk layout, see prepass.
    // addr(mi; slab,tap,ki) = gA2[mi] + slab*73728 + tap*8192 + ki*4096
    const unsigned short* gA2[4];
    {
        const unsigned short* base = wt2
            + (size_t)(b * 2 + mb) * 147456 + wm2 * 2048 + lane * 8;
        #pragma unroll
        for (int mi = 0; mi < 4; ++mi) gA2[mi] = base + mi * 512;
    }

    // ---- X-DMA map: wave wv stages X row rr=wv (global row ph0-1+wv).
    const int kcl = (lane & 7) ^ ((1 + (lane >> 3)) & 7);
    const int xsrc_lane = (lane >> 3) * CIN + kcl * 8;   // u16 offset in xt row
    const int hhx = ph0 - 1 + wv;
    const bool vrow = ((unsigned)hhx < 64u);
    unsigned short* const xdst = &Xs[(wv * 66 + 1) * 64];

    // ---- B frag-read constants (XOR chunk swizzle, as v4)
    int xoff[4];
    #pragma unroll
    for (int ni = 0; ni < 4; ++ni) xoff[ni] = (ni * 16 + l15 + 1) * 64;
    int xr[3][2];
    #pragma unroll
    for (int dxi = 0; dxi < 3; ++dxi)
        #pragma unroll
        for (int ki = 0; ki < 2; ++ki)
            xr[dxi][ki] = ((ki * 4 + q) ^ ((l15 + dxi) & 7)) * 8;

    f32x4 acc[4][4];
    #pragma unroll
    for (int i = 0; i < 4; ++i)
        #pragma unroll
        for (int j = 0; j < 4; ++j)
            acc[i][j] = (f32x4){0.f, 0.f, 0.f, 0.f};

    // ---- zero the column-halo cells of Xs once (cc=0 and cc=65, all 4 rows)
    {
        const int cell = tid >> 5;                 // 0..7
        const int rr   = cell >> 1;
        const int cc   = (cell & 1) ? 65 : 0;
        *reinterpret_cast<unsigned int*>(
            &Xs[(rr * 66 + cc) * 64 + (tid & 31) * 2]) = 0u;
    }

    auto stage_x = [&](int i0) {
        const unsigned short* sx = vrow
            ? xtb + (size_t)hhx * HW * CIN + i0 + xsrc_lane
            : g_zeros;
        #pragma unroll
        for (int g = 0; g < 8; ++g)
            gl_lds16(vrow ? (sx + g * 8 * CIN) : sx, xdst + g * 512);
    };

    #pragma unroll
    for (int s2 = 0; s2 < 2; ++s2) {
        const int sofs = s2 * 73728;               // slab offset (elems)

        if (s2) __syncthreads();                   // slab0 Xs reads complete

        // ring prologue: phases 0,1 of this slab (latency hides under stage_x)
        frag afr[3][4];
        #pragma unroll
        for (int mi = 0; mi < 4; ++mi) {
            afr[0][mi] = *reinterpret_cast<const frag*>(gA2[mi] + sofs);
            afr[1][mi] = *reinterpret_cast<const frag*>(gA2[mi] + sofs + 4096);
        }

        stage_x(s2 * 64);
        __syncthreads();                           // drains DMA: Xs (+A p0/p1) ready

        #pragma unroll
        for (int p = 0; p < 18; ++p) {
            // depth-2 prefetch: issue phase p+2 before computing phase p
            if (p + 2 < 18) {
                const int np   = p + 2;
                const int noff = sofs + (np >> 1) * 8192 + (np & 1) * 4096;
                #pragma unroll
                for (int mi = 0; mi < 4; ++mi)
                    afr[(p + 2) % 3][mi] =
                        *reinterpret_cast<const frag*>(gA2[mi] + noff);
            }
            const int tap = p >> 1;
            const int ki  = p & 1;
            const int dy  = tap / 3 - 1;
            const int dx  = tap - 3 * (tap / 3) - 1;
            const int dxi = dx + 1;
            const int cb  = (wnrow + dy + 1) * 4224 + dx * 64;  // 66*64 = 4224

            frag bfr[4];
            #pragma unroll
            for (int ni = 0; ni < 4; ++ni)
                bfr[ni] = *reinterpret_cast<const frag*>(
                    &Xs[cb + xoff[ni] + xr[dxi][ki]]);

            __builtin_amdgcn_s_setprio(1);
            #pragma unroll
            for (int mi = 0; mi < 4; ++mi)
                #pragma unroll
                for (int ni = 0; ni < 4; ++ni)
                    acc[mi][ni] = __builtin_amdgcn_mfma_f32_16x16x32_bf16(
                        afr[p % 3][mi], bfr[ni], acc[mi][ni], 0, 0, 0);
            __builtin_amdgcn_s_setprio(0);
        }
    }

    // ---- epilogue: D row=(q*4+reg), col=l15 ; add dropped-out bias
    float* ob = out + (size_t)b * COUT * NSP;
    #pragma unroll
    for (int mi = 0; mi < 4; ++mi) {
        #pragma unroll
        for (int rg = 0; rg < 4; ++rg) {
            const int o  = m0 + wm + mi * 16 + q * 4 + rg;
            const float bvv = (u_b[b * COUT + o] > PDROP) ? bias[o] : 0.f;
            float* orow = ob + (size_t)o * NSP + n0 + wn + l15;
            #pragma unroll
            for (int ni = 0; ni < 4; ++ni)
                orow[ni * 16] = acc[mi][ni][rg] + bvv;
        }
    }
}

// ---------------------------------------------------------------------------
// Fallback (round-1 kernel, no workspace): used only if workspace too small.
__global__ __launch_bounds__(256) void conv_fb(
        const float* __restrict__ x, const float* __restrict__ weight,
        const float* __restrict__ bias, const float* __restrict__ u_w,
        const float* __restrict__ u_b, float* __restrict__ out)
{
    using frag  = __attribute__((ext_vector_type(8))) short;
    using f32x4 = __attribute__((ext_vector_type(4))) float;

    __shared__ unsigned short As[128 * LDT];
    __shared__ unsigned short Bs[128 * LDT];

    const int tid  = threadIdx.x;
    const int lane = tid & 63;
    const int q    = lane >> 4;
    const int l15  = lane & 15;
    const int wv   = tid >> 6;
    const int wm   = (wv >> 1) * 64;
    const int wn   = (wv & 1) * 64;

    const int b  = blockIdx.z;
    const int m0 = blockIdx.y * 128;
    const int n0 = blockIdx.x * 128;

    const int arow = tid >> 1;
    const int acol = (tid & 1) * 16;
    const int pn = tid & 127;
    const int kh = (tid >> 7) * 16;
    const int p  = n0 + pn;
    const int ph = p >> 6;
    const int pw = p & 63;

    const float* xb = x + (size_t)b * CIN * NSP;

    f32x4 acc[4][4];
    #pragma unroll
    for (int i = 0; i < 4; ++i)
        #pragma unroll
        for (int j = 0; j < 4; ++j)
            acc[i][j] = (f32x4){0.f, 0.f, 0.f, 0.f};

    const int a_rd = (wm + l15) * LDT + q * 8;
    const int b_rd = (wn + l15) * LDT + q * 8;

    for (int s = 0; s < 36; ++s) {
        const int r  = s >> 2;
        const int i0 = (s & 3) * 32;

        float aw[16], au[16];
        {
            const float* wsrc = weight + (size_t)(m0 + arow) * KTOT;
            const float* usrc = u_w + (size_t)(b * COUT + m0 + arow) * KTOT;
            #pragma unroll
            for (int ii = 0; ii < 16; ++ii) {
                const int kk = (i0 + acol + ii) * 9 + r;
                aw[ii] = wsrc[kk];
                au[ii] = usrc[kk];
            }
        }

        const int hh = ph + (r / 3) - 1;
        const int ww = pw + (r % 3) - 1;
        float bx[16];
        #pragma unroll
        for (int j = 0; j < 16; ++j) bx[j] = 0.f;
        if (((unsigned)hh < 64u) && ((unsigned)ww < 64u)) {
            const float* xsrc = xb + (size_t)(i0 + kh) * NSP + hh * HW + ww;
            #pragma unroll
            for (int j = 0; j < 16; ++j) bx[j] = xsrc[(size_t)j * NSP];
        }

        __syncthreads();

        {
            union { unsigned short u16[16]; uint4 v[2]; } tu;
            #pragma unroll
            for (int ii = 0; ii < 16; ++ii)
                tu.u16[ii] = f2bf((au[ii] > PDROP) ? aw[ii] : 0.f);
            uint4* d = reinterpret_cast<uint4*>(&As[arow * LDT + acol]);
            d[0] = tu.v[0]; d[1] = tu.v[1];
        }
        {
            union { unsigned short u16[16]; uint4 v[2]; } tu;
            #pragma unroll
            for (int j = 0; j < 16; ++j) tu.u16[j] = f2bf(bx[j]);
            uint4* d = reinterpret_cast<uint4*>(&Bs[pn * LDT + kh]);
            d[0] = tu.v[0]; d[1] = tu.v[1];
        }

        __syncthreads();

        frag af[4], bfr[4];
        #pragma unroll
        for (int mi = 0; mi < 4; ++mi)
            af[mi] = *reinterpret_cast<const frag*>(&As[a_rd + mi * 16 * LDT]);
        #pragma unroll
        for (int ni = 0; ni < 4; ++ni)
            bfr[ni] = *reinterpret_cast<const frag*>(&Bs[b_rd + ni * 16 * LDT]);
        #pragma unroll
        for (int mi = 0; mi < 4; ++mi)
            #pragma unroll
            for (int ni = 0; ni < 4; ++ni)
                acc[mi][ni] = __builtin_amdgcn_mfma_f32_16x16x32_bf16(
                    af[mi], bfr[ni], acc[mi][ni], 0, 0, 0);
    }

    float* ob = out + (size_t)b * COUT * NSP;
    #pragma unroll
    for (int mi = 0; mi < 4; ++mi) {
        #pragma unroll
        for (int rg = 0; rg < 4; ++rg) {
            const int o = m0 + wm + mi * 16 + q * 4 + rg;
            const float bvv = (u_b[b * COUT + o] > PDROP) ? bias[o] : 0.f;
            float* orow = ob + (size_t)o * NSP + n0 + wn + l15;
            #pragma unroll
            for (int ni = 0; ni < 4; ++ni)
                orow[ni * 16] = acc[mi][ni][rg] + bvv;
        }
    }
}

extern "C" void kernel_launch(void* const* d_in, const int* in_sizes, int n_in,
                              void* d_out, int out_size, void* d_ws, size_t ws_size,
                              hipStream_t stream)
{
    const float* x      = (const float*)d_in[0];
    const float* weight = (const float*)d_in[1];
    const float* bias   = (const float*)d_in[2];
    const float* u_w    = (const float*)d_in[3];
    const float* u_b    = (const float*)d_in[4];
    float* out = (float*)d_out;

    const size_t wt_bytes = (size_t)BATCH * COUT * KTOT * sizeof(unsigned short); // 18.87 MB
    const size_t xt_bytes = (size_t)BATCH * NSP * CIN * sizeof(unsigned short);   // 33.55 MB
    dim3 grid(NSP / 128, COUT / 128, BATCH);   // 32 x 2 x 32 = 2048 blocks

    if (ws_size >= wt_bytes + xt_bytes) {
        unsigned short* wtp = (unsigned short*)d_ws;
        unsigned short* xtp = (unsigned short*)((char*)d_ws + wt_bytes);
        prepass<<<512 + 2048, 256, 0, stream>>>(weight, u_w, x, wtp, xtp);
        conv_v7<<<grid, 256, 0, stream>>>(wtp, xtp, bias, u_b, out);
    } else {
        conv_fb<<<grid, 256, 0, stream>>>(x, weight, bias, u_w, u_b, out);
    }
}

// Round 4
// 278.953 us; speedup vs baseline: 1.2648x; 1.0336x over previous
//
#include <hip/hip_runtime.h>
#include <cstdint>
#include <cstddef>

#define CIN   128
#define COUT  256
#define HW    64
#define NSP   4096      // 64*64 spatial
#define KTOT  1152      // CIN*9
#define BATCH 32
#define PDROP 0.2f
#define LDT   40        // fallback conv LDS stride (bf16 elems)
#define WLD   1160      // prepass weight tile stride (elems)

__device__ __forceinline__ unsigned short f2bf(float f) {
    unsigned int u = __builtin_bit_cast(unsigned int, f);
    u += 0x7fffu + ((u >> 16) & 1u);   // round-to-nearest-even
    return (unsigned short)(u >> 16);
}

// 128 B of guaranteed zeros for OOB halo DMA source (never written)
__device__ __align__(16) unsigned short g_zeros[64] = {0};

// async global->LDS, 16 B per lane; LDS dest = wave-uniform base + lane*16
__device__ __forceinline__ void gl_lds16(const unsigned short* g, unsigned short* l) {
    __builtin_amdgcn_global_load_lds(
        (const __attribute__((address_space(1))) unsigned int*)g,
        (__attribute__((address_space(3))) unsigned int*)l,
        16, 0, 0);
}

// ---------------------------------------------------------------------------
// wt2 layout (16-B chunk units):
//   chunk = (((((b*2+mb)*2+slab)*9+tap)*2+ki)*2+wm2)*256 + mi*64 + (q*16+l15)
// Conv A-load for wave(wm2), phase(slab,tap,ki), frag mi is then exactly
//   base + lane*16  (lane = q*16+l15)  -> ideal coalesced 1 KiB/instruction.
// Chunk content: masked bf16 weight row o = mb*128+wm2*64+mi*16+l15,
//   channels i = slab*64+ki*32+q*8 .. +8, tap r  (flat OIHW k = i*9+r).
// ---------------------------------------------------------------------------
// Fused pre-pass (single launch):
//  blocks [0,512):    weight -> wt2 fragment-major. Block owns (b,mb,wm2,mi)
//                     = 16 rows. READS ARE FULLY COALESCED (flat float4 over
//                     the 16x1152 region; r3's 288-B-stride reads were 64
//                     scattered lines/instr). LDS tap-major transpose, then
//                     contiguous 1-KB coalesced writes.
//  blocks [512,2560): x NCHW fp32 -> xt[b][hw][ch] bf16 (NHWC), via u32
//                     channel-pair tile stride 65 (2-way free both phases).
__global__ __launch_bounds__(256) void prepass(
        const float* __restrict__ weight, const float* __restrict__ u_w,
        const float* __restrict__ x,
        unsigned short* __restrict__ wt2, unsigned short* __restrict__ xt)
{
    __shared__ __align__(16) unsigned char smem[16 * WLD * 2];   // 37120 B
    const int t256 = threadIdx.x;

    if (blockIdx.x < 512) {
        unsigned short* tile16 = reinterpret_cast<unsigned short*>(smem);
        const int wb  = blockIdx.x;
        const int b   = wb >> 4;
        const int mb  = (wb >> 3) & 1;
        const int wm2 = (wb >> 2) & 1;
        const int mi  = wb & 3;
        const int obase = mb * 128 + wm2 * 64 + mi * 16;

        // ---- coalesced load + mask + LDS transpose to tile16[row][r*128+i]
        // Flat float region [0, 16*1152) over the block's 16 o-rows.
        const float* wsrc = weight + (size_t)obase * KTOT;
        const float* usrc = u_w + (size_t)(b * COUT + obase) * KTOT;
        #pragma unroll
        for (int j = 0; j < 18; ++j) {
            const int f4 = j * 256 + t256;          // 0..4607 float4s, contiguous
            const float4 wv = reinterpret_cast<const float4*>(wsrc)[f4];
            const float4 uv = reinterpret_cast<const float4*>(usrc)[f4];
            const float w4[4] = {wv.x, wv.y, wv.z, wv.w};
            const float u4[4] = {uv.x, uv.y, uv.z, uv.w};
            #pragma unroll
            for (int e = 0; e < 4; ++e) {
                const int fl  = f4 * 4 + e;         // flat elem in 16x1152
                const int row = fl / KTOT;          // const-div -> mul/shift
                const int ks  = fl - row * KTOT;    // i*9 + r
                const int i   = ks / 9;
                const int r   = ks - 9 * i;
                tile16[row * WLD + r * CIN + i] =
                    f2bf((u4[e] > PDROP) ? w4[e] : 0.f);
            }
        }
        __syncthreads();

        // ---- write phase: 36 runs x 1 KB, fully coalesced
        const size_t blk16 = ((size_t)(b * 2 + mb)) * 18432;   // chunk units
        #pragma unroll
        for (int s = 0; s < 9; ++s) {
            const int g     = s * 256 + t256;      // 0..2303
            const int run   = g >> 6;              // 0..35
            const int inner = g & 63;              // q*16 + l15
            const int slab  = run >= 18;
            const int rr    = run - slab * 18;
            const int tap   = rr >> 1;
            const int ki    = rr & 1;
            const int q     = inner >> 4;
            const int il15  = inner & 15;
            const uint4 v = *reinterpret_cast<const uint4*>(
                &tile16[il15 * WLD + tap * CIN + slab * 64 + ki * 32 + q * 8]);
            const size_t dst16 = blk16
                + (size_t)(((slab * 9 + tap) * 2 + ki) * 2 + wm2) * 256
                + mi * 64 + inner;
            *reinterpret_cast<uint4*>(wt2 + dst16 * 8) = v;
        }
    } else {
        unsigned int* shp = reinterpret_cast<unsigned int*>(smem);
        const int bidx = blockIdx.x - 512;
        const int b    = bidx >> 6;
        const int hw0  = (bidx & 63) * 64;
        const int ib   = t256 >> 4;                // 0..15
        const int hw4  = (t256 & 15) * 4;          // local hw row group
        #pragma unroll
        for (int j = 0; j < 4; ++j) {
            const int p = ib + 16 * j;             // channel-pair 0..63
            const float4 v0 = *reinterpret_cast<const float4*>(
                x + ((size_t)(b * CIN + 2 * p)) * NSP + hw0 + hw4);
            const float4 v1 = *reinterpret_cast<const float4*>(
                x + ((size_t)(b * CIN + 2 * p + 1)) * NSP + hw0 + hw4);
            const float e0[4] = {v0.x, v0.y, v0.z, v0.w};
            const float e1[4] = {v1.x, v1.y, v1.z, v1.w};
            #pragma unroll
            for (int c = 0; c < 4; ++c) {
                const unsigned int val =
                    (unsigned int)f2bf(e0[c]) | ((unsigned int)f2bf(e1[c]) << 16);
                shp[(hw4 + c) * 65 + p] = val;     // bank=(hw+p)%32: 2-way free
            }
        }
        __syncthreads();
        #pragma unroll
        for (int j = 0; j < 4; ++j) {
            const int idx  = j * 256 + t256;       // 0..1023
            const int row  = idx >> 4;             // hw_loc 0..63
            const int part = idx & 15;             // 16 B chunk (4 u32 pairs)
            uint4 v;
            v.x = shp[row * 65 + part * 4 + 0];
            v.y = shp[row * 65 + part * 4 + 1];
            v.z = shp[row * 65 + part * 4 + 2];
            v.w = shp[row * 65 + part * 4 + 3];
            *reinterpret_cast<uint4*>(
                xt + ((size_t)(b * NSP + hw0 + row)) * CIN + part * 8) = v;
        }
    }
}

// ---------------------------------------------------------------------------
// Main conv v8: v7 structure (LDS-resident X-tile, fragment-major wt2 with
// coalesced direct-to-reg A ring depth-2, 3 barriers total, XCD-clustered
// swizzle) + B-FRAGMENT REGISTER RING depth-1: the 4 ds_read_b128 for phase
// p+1 issue BEFORE phase p's MFMA cluster (outside the setprio region), so
// the per-wave lgkm wait lands after ~310 cycles of MFMA instead of directly
// before the cluster. Removes the per-phase LDS-latency bubble (T14 on LDS).
__global__ __launch_bounds__(256, 3) void conv_v8(
        const unsigned short* __restrict__ wt2,
        const unsigned short* __restrict__ xt,
        const float* __restrict__ bias, const float* __restrict__ u_b,
        float* __restrict__ out)
{
    using frag  = __attribute__((ext_vector_type(8))) short;
    using f32x4 = __attribute__((ext_vector_type(4))) float;

    __shared__ unsigned short Xs[4 * 66 * 64];     // 33792 B resident x-tile

    const int tid  = threadIdx.x;
    const int lane = tid & 63;
    const int q    = lane >> 4;
    const int l15  = lane & 15;
    const int wv   = tid >> 6;
    const int wm   = (wv >> 1) * 64;
    const int wn   = (wv & 1) * 64;
    const int wnrow = wn >> 6;                     // 0 or 1: tile spatial row
    const int wm2  = wv >> 1;

    // ---- XCD-clustered bijective swizzle (grid = 32 x 2 x 32 = 2048, %8==0)
    const int f   = blockIdx.x + 32 * blockIdx.y + 64 * blockIdx.z;
    const int wid = (f & 7) * 256 + (f >> 3);
    const int b   = wid >> 6;
    const int m0  = ((wid >> 5) & 1) * 128;
    const int n0  = (wid & 31) * 128;
    const int mb  = m0 >> 7;
    const int ph0 = n0 >> 6;                       // first global image row

    const unsigned short* xtb = xt + (size_t)b * NSP * CIN;

    // ---- A-fragment base pointers (elems): wt2 chunk layout, see prepass.
    // addr(mi; slab,tap,ki) = gA2[mi] + slab*73728 + tap*8192 + ki*4096
    const unsigned short* gA2[4];
    {
        const unsigned short* base = wt2
            + (size_t)(b * 2 + mb) * 147456 + wm2 * 2048 + lane * 8;
        #pragma unroll
        for (int mi = 0; mi < 4; ++mi) gA2[mi] = base + mi * 512;
    }

    // ---- X-DMA map: wave wv stages X row rr=wv (global row ph0-1+wv).
    const int kcl = (lane & 7) ^ ((1 + (lane >> 3)) & 7);
    const int xsrc_lane = (lane >> 3) * CIN + kcl * 8;   // u16 offset in xt row
    const int hhx = ph0 - 1 + wv;
    const bool vrow = ((unsigned)hhx < 64u);
    unsigned short* const xdst = &Xs[(wv * 66 + 1) * 64];

    // ---- B frag-read constants (XOR chunk swizzle, as v4)
    int xoff[4];
    #pragma unroll
    for (int ni = 0; ni < 4; ++ni) xoff[ni] = (ni * 16 + l15 + 1) * 64;
    int xr[3][2];
    #pragma unroll
    for (int dxi = 0; dxi < 3; ++dxi)
        #pragma unroll
        for (int ki = 0; ki < 2; ++ki)
            xr[dxi][ki] = ((ki * 4 + q) ^ ((l15 + dxi) & 7)) * 8;

    f32x4 acc[4][4];
    #pragma unroll
    for (int i = 0; i < 4; ++i)
        #pragma unroll
        for (int j = 0; j < 4; ++j)
            acc[i][j] = (f32x4){0.f, 0.f, 0.f, 0.f};

    // ---- zero the column-halo cells of Xs once (cc=0 and cc=65, all 4 rows)
    {
        const int cell = tid >> 5;                 // 0..7
        const int rr   = cell >> 1;
        const int cc   = (cell & 1) ? 65 : 0;
        *reinterpret_cast<unsigned int*>(
            &Xs[(rr * 66 + cc) * 64 + (tid & 31) * 2]) = 0u;
    }

    auto stage_x = [&](int i0) {
        const unsigned short* sx = vrow
            ? xtb + (size_t)hhx * HW * CIN + i0 + xsrc_lane
            : g_zeros;
        #pragma unroll
        for (int g = 0; g < 8; ++g)
            gl_lds16(vrow ? (sx + g * 8 * CIN) : sx, xdst + g * 512);
    };

    // B-fragment loader for phase pp (0..17) of current slab
    auto loadB = [&](int pp, frag* dst) {
        const int tap = pp >> 1;
        const int ki  = pp & 1;
        const int dy  = tap / 3 - 1;
        const int dx  = tap - 3 * (tap / 3) - 1;
        const int dxi = dx + 1;
        const int cb  = (wnrow + dy + 1) * 4224 + dx * 64;  // 66*64 = 4224
        #pragma unroll
        for (int ni = 0; ni < 4; ++ni)
            dst[ni] = *reinterpret_cast<const frag*>(
                &Xs[cb + xoff[ni] + xr[dxi][ki]]);
    };

    #pragma unroll
    for (int s2 = 0; s2 < 2; ++s2) {
        const int sofs = s2 * 73728;               // slab offset (elems)

        if (s2) __syncthreads();                   // slab0 Xs reads complete

        // A ring prologue: phases 0,1 (latency hides under stage_x + barrier)
        frag afr[3][4];
        #pragma unroll
        for (int mi = 0; mi < 4; ++mi) {
            afr[0][mi] = *reinterpret_cast<const frag*>(gA2[mi] + sofs);
            afr[1][mi] = *reinterpret_cast<const frag*>(gA2[mi] + sofs + 4096);
        }

        stage_x(s2 * 64);
        __syncthreads();                           // drains DMA: Xs (+A p0/p1) ready

        // B ring prologue: phase 0
        frag bring[2][4];
        loadB(0, bring[0]);

        #pragma unroll
        for (int p = 0; p < 18; ++p) {
            // depth-2 A prefetch (global, coalesced 1 KiB/instr)
            if (p + 2 < 18) {
                const int np   = p + 2;
                const int noff = sofs + (np >> 1) * 8192 + (np & 1) * 4096;
                #pragma unroll
                for (int mi = 0; mi < 4; ++mi)
                    afr[(p + 2) % 3][mi] =
                        *reinterpret_cast<const frag*>(gA2[mi] + noff);
            }
            // depth-1 B prefetch (LDS) -- issued BEFORE this phase's MFMAs
            if (p + 1 < 18) loadB(p + 1, bring[(p + 1) & 1]);

            __builtin_amdgcn_s_setprio(1);
            #pragma unroll
            for (int mi = 0; mi < 4; ++mi)
                #pragma unroll
                for (int ni = 0; ni < 4; ++ni)
                    acc[mi][ni] = __builtin_amdgcn_mfma_f32_16x16x32_bf16(
                        afr[p % 3][mi], bring[p & 1][ni], acc[mi][ni], 0, 0, 0);
            __builtin_amdgcn_s_setprio(0);
        }
    }

    // ---- epilogue: D row=(q*4+reg), col=l15 ; add dropped-out bias
    float* ob = out + (size_t)b * COUT * NSP;
    #pragma unroll
    for (int mi = 0; mi < 4; ++mi) {
        #pragma unroll
        for (int rg = 0; rg < 4; ++rg) {
            const int o  = m0 + wm + mi * 16 + q * 4 + rg;
            const float bvv = (u_b[b * COUT + o] > PDROP) ? bias[o] : 0.f;
            float* orow = ob + (size_t)o * NSP + n0 + wn + l15;
            #pragma unroll
            for (int ni = 0; ni < 4; ++ni)
                orow[ni * 16] = acc[mi][ni][rg] + bvv;
        }
    }
}

// ---------------------------------------------------------------------------
// Fallback (round-1 kernel, no workspace): used only if workspace too small.
__global__ __launch_bounds__(256) void conv_fb(
        const float* __restrict__ x, const float* __restrict__ weight,
        const float* __restrict__ bias, const float* __restrict__ u_w,
        const float* __restrict__ u_b, float* __restrict__ out)
{
    using frag  = __attribute__((ext_vector_type(8))) short;
    using f32x4 = __attribute__((ext_vector_type(4))) float;

    __shared__ unsigned short As[128 * LDT];
    __shared__ unsigned short Bs[128 * LDT];

    const int tid  = threadIdx.x;
    const int lane = tid & 63;
    const int q    = lane >> 4;
    const int l15  = lane & 15;
    const int wv   = tid >> 6;
    const int wm   = (wv >> 1) * 64;
    const int wn   = (wv & 1) * 64;

    const int b  = blockIdx.z;
    const int m0 = blockIdx.y * 128;
    const int n0 = blockIdx.x * 128;

    const int arow = tid >> 1;
    const int acol = (tid & 1) * 16;
    const int pn = tid & 127;
    const int kh = (tid >> 7) * 16;
    const int p  = n0 + pn;
    const int ph = p >> 6;
    const int pw = p & 63;

    const float* xb = x + (size_t)b * CIN * NSP;

    f32x4 acc[4][4];
    #pragma unroll
    for (int i = 0; i < 4; ++i)
        #pragma unroll
        for (int j = 0; j < 4; ++j)
            acc[i][j] = (f32x4){0.f, 0.f, 0.f, 0.f};

    const int a_rd = (wm + l15) * LDT + q * 8;
    const int b_rd = (wn + l15) * LDT + q * 8;

    for (int s = 0; s < 36; ++s) {
        const int r  = s >> 2;
        const int i0 = (s & 3) * 32;

        float aw[16], au[16];
        {
            const float* wsrc = weight + (size_t)(m0 + arow) * KTOT;
            const float* usrc = u_w + (size_t)(b * COUT + m0 + arow) * KTOT;
            #pragma unroll
            for (int ii = 0; ii < 16; ++ii) {
                const int kk = (i0 + acol + ii) * 9 + r;
                aw[ii] = wsrc[kk];
                au[ii] = usrc[kk];
            }
        }

        const int hh = ph + (r / 3) - 1;
        const int ww = pw + (r % 3) - 1;
        float bx[16];
        #pragma unroll
        for (int j = 0; j < 16; ++j) bx[j] = 0.f;
        if (((unsigned)hh < 64u) && ((unsigned)ww < 64u)) {
            const float* xsrc = xb + (size_t)(i0 + kh) * NSP + hh * HW + ww;
            #pragma unroll
            for (int j = 0; j < 16; ++j) bx[j] = xsrc[(size_t)j * NSP];
        }

        __syncthreads();

        {
            union { unsigned short u16[16]; uint4 v[2]; } tu;
            #pragma unroll
            for (int ii = 0; ii < 16; ++ii)
                tu.u16[ii] = f2bf((au[ii] > PDROP) ? aw[ii] : 0.f);
            uint4* d = reinterpret_cast<uint4*>(&As[arow * LDT + acol]);
            d[0] = tu.v[0]; d[1] = tu.v[1];
        }
        {
            union { unsigned short u16[16]; uint4 v[2]; } tu;
            #pragma unroll
            for (int j = 0; j < 16; ++j) tu.u16[j] = f2bf(bx[j]);
            uint4* d = reinterpret_cast<uint4*>(&Bs[pn * LDT + kh]);
            d[0] = tu.v[0]; d[1] = tu.v[1];
        }

        __syncthreads();

        frag af[4], bfr[4];
        #pragma unroll
        for (int mi = 0; mi < 4; ++mi)
            af[mi] = *reinterpret_cast<const frag*>(&As[a_rd + mi * 16 * LDT]);
        #pragma unroll
        for (int ni = 0; ni < 4; ++ni)
            bfr[ni] = *reinterpret_cast<const frag*>(&Bs[b_rd + ni * 16 * LDT]);
        #pragma unroll
        for (int mi = 0; mi < 4; ++mi)
            #pragma unroll
            for (int ni = 0; ni < 4; ++ni)
                acc[mi][ni] = __builtin_amdgcn_mfma_f32_16x16x32_bf16(
                    af[mi], bfr[ni], acc[mi][ni], 0, 0, 0);
    }

    float* ob = out + (size_t)b * COUT * NSP;
    #pragma unroll
    for (int mi = 0; mi < 4; ++mi) {
        #pragma unroll
        for (int rg = 0; rg < 4; ++rg) {
            const int o = m0 + wm + mi * 16 + q * 4 + rg;
            const float bvv = (u_b[b * COUT + o] > PDROP) ? bias[o] : 0.f;
            float* orow = ob + (size_t)o * NSP + n0 + wn + l15;
            #pragma unroll
            for (int ni = 0; ni < 4; ++ni)
                orow[ni * 16] = acc[mi][ni][rg] + bvv;
        }
    }
}

extern "C" void kernel_launch(void* const* d_in, const int* in_sizes, int n_in,
                              void* d_out, int out_size, void* d_ws, size_t ws_size,
                              hipStream_t stream)
{
    const float* x      = (const float*)d_in[0];
    const float* weight = (const float*)d_in[1];
    const float* bias   = (const float*)d_in[2];
    const float* u_w    = (const float*)d_in[3];
    const float* u_b    = (const float*)d_in[4];
    float* out = (float*)d_out;

    const size_t wt_bytes = (size_t)BATCH * COUT * KTOT * sizeof(unsigned short); // 18.87 MB
    const size_t xt_bytes = (size_t)BATCH * NSP * CIN * sizeof(unsigned short);   // 33.55 MB
    dim3 grid(NSP / 128, COUT / 128, BATCH);   // 32 x 2 x 32 = 2048 blocks

    if (ws_size >= wt_bytes + xt_bytes) {
        unsigned short* wtp = (unsigned short*)d_ws;
        unsigned short* xtp = (unsigned short*)((char*)d_ws + wt_bytes);
        prepass<<<512 + 2048, 256, 0, stream>>>(weight, u_w, x, wtp, xtp);
        conv_v8<<<grid, 256, 0, stream>>>(wtp, xtp, bias, u_b, out);
    } else {
        conv_fb<<<grid, 256, 0, stream>>>(x, weight, bias, u_w, u_b, out);
    }
}